// Round 1
// baseline (89.173 us; speedup 1.0000x reference)
//
#include <hip/hip_runtime.h>
#include <math.h>

constexpr int N = 8192;
constexpr int K = 30;
constexpr int TPB = 256;
constexpr int NI_BLOCKS = N / TPB;          // 32
constexpr int NJ_SLICES = 8;
constexpr int JCHUNK = TPB;                 // 256
constexpr int NBLOCKS2 = NI_BLOCKS * NJ_SLICES;  // 256
constexpr int JSPAN = N / NJ_SLICES;        // 1024

// d_ws layout (doubles):
//   [0, N)               : mrl[i]
//   [N, N + 2*NBLOCKS2)  : per-block partials {num, cnt} interleaved

__global__ void mrl_kernel(const float* __restrict__ est,
                           const float* __restrict__ intervals,
                           double* __restrict__ mrl) {
    int i = blockIdx.x * blockDim.x + threadIdx.x;
    if (i >= N) return;
    const float* e = est + (size_t)i * K;
    double sp = 1.0;   // surv_prev
    double m  = 0.0;
#pragma unroll
    for (int k = 0; k < K; ++k) {
        double x = (double)e[k];
        double h = 1.0 / (1.0 + exp(-x));   // sigmoid
        m += (double)intervals[k] * h * sp; // intervals[k] * pdf[k]
        sp *= (1.0 - h);
    }
    mrl[i] = m;
}

__global__ void pair_kernel(const float* __restrict__ target,
                            const double* __restrict__ mrl,
                            double* __restrict__ partials) {
    __shared__ float  s_t[JCHUNK];
    __shared__ double s_m[JCHUNK];
    __shared__ double r_num[TPB];
    __shared__ double r_cnt[TPB];

    const int tid = threadIdx.x;
    const int ib  = blockIdx.x / NJ_SLICES;
    const int js  = blockIdx.x % NJ_SLICES;
    const int i   = ib * TPB + tid;

    const float  ti = target[2 * i];
    const bool   ei = (target[2 * i + 1] != 0.0f);
    const double mi = mrl[i];

    const int jlo = js * JSPAN;
    const int jhi = jlo + JSPAN;

    int    cnt = 0;
    double smj = 0.0;

    for (int j0 = jlo; j0 < jhi; j0 += JCHUNK) {
        const int j = j0 + tid;
        s_t[tid] = target[2 * j];
        s_m[tid] = mrl[j];
        __syncthreads();
        if (ei) {
#pragma unroll 8
            for (int jj = 0; jj < JCHUNK; ++jj) {
                // broadcast LDS reads (same address all lanes) -> conflict-free
                if (ti < s_t[jj]) { cnt++; smj += s_m[jj]; }
            }
        }
        __syncthreads();
    }

    r_num[tid] = ei ? ((double)cnt * mi - smj) : 0.0;
    r_cnt[tid] = ei ? (double)cnt : 0.0;
    __syncthreads();
    for (int s = TPB / 2; s > 0; s >>= 1) {
        if (tid < s) {
            r_num[tid] += r_num[tid + s];
            r_cnt[tid] += r_cnt[tid + s];
        }
        __syncthreads();
    }
    if (tid == 0) {
        partials[2 * blockIdx.x]     = r_num[0];
        partials[2 * blockIdx.x + 1] = r_cnt[0];
    }
}

__global__ void final_kernel(const double* __restrict__ partials,
                             float* __restrict__ out) {
    __shared__ double r_num[TPB];
    __shared__ double r_cnt[TPB];
    const int tid = threadIdx.x;
    // NBLOCKS2 == TPB, one partial pair per thread
    r_num[tid] = partials[2 * tid];
    r_cnt[tid] = partials[2 * tid + 1];
    __syncthreads();
    for (int s = TPB / 2; s > 0; s >>= 1) {
        if (tid < s) {
            r_num[tid] += r_num[tid + s];
            r_cnt[tid] += r_cnt[tid + s];
        }
        __syncthreads();
    }
    if (tid == 0) out[0] = (float)(r_num[0] / r_cnt[0]);
}

extern "C" void kernel_launch(void* const* d_in, const int* in_sizes, int n_in,
                              void* d_out, int out_size, void* d_ws, size_t ws_size,
                              hipStream_t stream) {
    const float* est       = (const float*)d_in[0];   // (N, K) fp32
    const float* target    = (const float*)d_in[1];   // (N, 2) fp32
    const float* intervals = (const float*)d_in[2];   // (K,)  fp32
    float* out = (float*)d_out;

    double* mrl      = (double*)d_ws;
    double* partials = mrl + N;

    mrl_kernel<<<NI_BLOCKS, TPB, 0, stream>>>(est, intervals, mrl);
    pair_kernel<<<NBLOCKS2, TPB, 0, stream>>>(target, mrl, partials);
    final_kernel<<<1, TPB, 0, stream>>>(partials, out);
}

// Round 2
// 24.444 us; speedup vs baseline: 3.6481x; 3.6481x over previous
//
#include <hip/hip_runtime.h>
#include <math.h>

constexpr int N = 8192;
constexpr int K = 30;
constexpr int TPB = 256;
constexpr int NI_BLOCKS = N / TPB;               // 32
constexpr int NJ_SLICES = 32;
constexpr int JSPAN = N / NJ_SLICES;             // 256 == TPB, one chunk per block
constexpr int NBLOCKS2 = NI_BLOCKS * NJ_SLICES;  // 1024

// d_ws layout (doubles):
//   [0, N)               : mrl[i]
//   [N, N + 2*NBLOCKS2)  : per-block partials {num, cnt} interleaved

__global__ void mrl_kernel(const float* __restrict__ est,
                           const float* __restrict__ intervals,
                           double* __restrict__ mrl) {
    int i = blockIdx.x * blockDim.x + threadIdx.x;
    if (i >= N) return;
    const float* e = est + (size_t)i * K;
    double sp = 1.0;   // surv_prev
    double m  = 0.0;
#pragma unroll
    for (int k = 0; k < K; ++k) {
        double x = (double)e[k];
        double h = 1.0 / (1.0 + exp(-x));   // sigmoid
        m += (double)intervals[k] * h * sp; // intervals[k] * pdf[k]
        sp *= (1.0 - h);
    }
    mrl[i] = m;
}

__global__ void __launch_bounds__(TPB, 4)
pair_kernel(const float* __restrict__ target,
            const double* __restrict__ mrl,
            double* __restrict__ partials) {
    __shared__ float  s_t[JSPAN];
    __shared__ double s_m[JSPAN];
    __shared__ double r_num[TPB];
    __shared__ double r_cnt[TPB];

    const int tid = threadIdx.x;
    const int ib  = blockIdx.x / NJ_SLICES;
    const int js  = blockIdx.x % NJ_SLICES;
    const int i   = ib * TPB + tid;
    const int j   = js * JSPAN + tid;

    const float  ti = target[2 * i];
    const bool   ei = (target[2 * i + 1] != 0.0f);
    const double mi = mrl[i];

    // stage this block's j-chunk
    s_t[tid] = target[2 * j];
    s_m[tid] = mrl[j];
    __syncthreads();

    // 4 independent accumulator chains for ILP (break the f64-add latency chain)
    int    c0 = 0, c1 = 0, c2 = 0, c3 = 0;
    double a0 = 0.0, a1 = 0.0, a2 = 0.0, a3 = 0.0;

#pragma unroll 8
    for (int jj = 0; jj < JSPAN; jj += 4) {
        // broadcast LDS reads (uniform address across lanes) -> conflict-free
        float  t0 = s_t[jj + 0], t1 = s_t[jj + 1], t2 = s_t[jj + 2], t3 = s_t[jj + 3];
        double m0 = s_m[jj + 0], m1 = s_m[jj + 1], m2 = s_m[jj + 2], m3 = s_m[jj + 3];
        bool b0 = ti < t0, b1 = ti < t1, b2 = ti < t2, b3 = ti < t3;
        c0 += b0; a0 += b0 ? m0 : 0.0;
        c1 += b1; a1 += b1 ? m1 : 0.0;
        c2 += b2; a2 += b2 ? m2 : 0.0;
        c3 += b3; a3 += b3 ? m3 : 0.0;
    }

    const int    cnt = c0 + c1 + c2 + c3;
    const double smj = (a0 + a1) + (a2 + a3);

    r_num[tid] = ei ? ((double)cnt * mi - smj) : 0.0;
    r_cnt[tid] = ei ? (double)cnt : 0.0;
    __syncthreads();
    for (int s = TPB / 2; s > 0; s >>= 1) {
        if (tid < s) {
            r_num[tid] += r_num[tid + s];
            r_cnt[tid] += r_cnt[tid + s];
        }
        __syncthreads();
    }
    if (tid == 0) {
        partials[2 * blockIdx.x]     = r_num[0];
        partials[2 * blockIdx.x + 1] = r_cnt[0];
    }
}

__global__ void final_kernel(const double* __restrict__ partials,
                             float* __restrict__ out) {
    __shared__ double r_num[TPB];
    __shared__ double r_cnt[TPB];
    const int tid = threadIdx.x;
    double n = 0.0, c = 0.0;
#pragma unroll
    for (int p = 0; p < NBLOCKS2 / TPB; ++p) {
        const int idx = p * TPB + tid;
        n += partials[2 * idx];
        c += partials[2 * idx + 1];
    }
    r_num[tid] = n;
    r_cnt[tid] = c;
    __syncthreads();
    for (int s = TPB / 2; s > 0; s >>= 1) {
        if (tid < s) {
            r_num[tid] += r_num[tid + s];
            r_cnt[tid] += r_cnt[tid + s];
        }
        __syncthreads();
    }
    if (tid == 0) out[0] = (float)(r_num[0] / r_cnt[0]);
}

extern "C" void kernel_launch(void* const* d_in, const int* in_sizes, int n_in,
                              void* d_out, int out_size, void* d_ws, size_t ws_size,
                              hipStream_t stream) {
    const float* est       = (const float*)d_in[0];   // (N, K) fp32
    const float* target    = (const float*)d_in[1];   // (N, 2) fp32
    const float* intervals = (const float*)d_in[2];   // (K,)  fp32
    float* out = (float*)d_out;

    double* mrl      = (double*)d_ws;
    double* partials = mrl + N;

    mrl_kernel<<<NI_BLOCKS, TPB, 0, stream>>>(est, intervals, mrl);
    pair_kernel<<<NBLOCKS2, TPB, 0, stream>>>(target, mrl, partials);
    final_kernel<<<1, TPB, 0, stream>>>(partials, out);
}